// Round 2
// baseline (1979.415 us; speedup 1.0000x reference)
//
#include <hip/hip_runtime.h>
#include <hip/hip_bf16.h>

#define N_NODES 100000
#define N_EDGES 3200000
#define IN_DIM 128
#define HIDDEN 64
#define N_GRAPHS 512

// ---------------- degree / normalization ----------------
__global__ void deg_init_kernel(float* __restrict__ deg) {
    int i = blockIdx.x * blockDim.x + threadIdx.x;
    if (i < N_NODES) deg[i] = 1.0f;   // self-loop
}

__global__ void deg_count_kernel(const int* __restrict__ dst, float* __restrict__ deg) {
    int e = blockIdx.x * blockDim.x + threadIdx.x;
    if (e < N_EDGES) atomicAdd(&deg[dst[e]], 1.0f);
}

__global__ void dis_kernel(float* __restrict__ deg) {
    int i = blockIdx.x * blockDim.x + threadIdx.x;
    if (i < N_NODES) deg[i] = rsqrtf(deg[i]);   // deg >= 1 always
}

// ---------------- layer 1 GEMM: h1 = x @ W1 ; out1 = h1 * dis^2 (self-loop init)
__global__ __launch_bounds__(256) void gemm1_kernel(
        const float* __restrict__ x, const float* __restrict__ W1,
        const float* __restrict__ dis,
        float* __restrict__ h1, float* __restrict__ out1) {
    __shared__ float Wl[IN_DIM * HIDDEN];   // 32 KB
    __shared__ float xl[4][IN_DIM];
    int tid = threadIdx.x;
    for (int i = tid; i < IN_DIM * HIDDEN; i += 256) Wl[i] = W1[i];
    int w = tid >> 6, lane = tid & 63;
    int node = blockIdx.x * 4 + w;
    if (node < N_NODES) {
        xl[w][lane]      = x[node * IN_DIM + lane];
        xl[w][lane + 64] = x[node * IN_DIM + lane + 64];
    }
    __syncthreads();
    if (node < N_NODES) {
        float acc = 0.f;
        #pragma unroll
        for (int k = 0; k < IN_DIM; ++k)
            acc = fmaf(xl[w][k], Wl[k * HIDDEN + lane], acc);
        h1[node * HIDDEN + lane] = acc;
        float d = dis[node];
        out1[node * HIDDEN + lane] = acc * d * d;
    }
}

// ---------------- edge scatter: out[dst] += h[src] * dis[src]*dis[dst]
__global__ __launch_bounds__(256) void scatter_kernel(
        const int* __restrict__ src, const int* __restrict__ dst,
        const float* __restrict__ dis, const float* __restrict__ h,
        float* __restrict__ out) {
    int w = threadIdx.x >> 6, lane = threadIdx.x & 63;
    int e = blockIdx.x * 4 + w;
    if (e < N_EDGES) {
        int s = src[e], d = dst[e];
        float nrm = dis[s] * dis[d];
        float v = h[s * HIDDEN + lane] * nrm;
        atomicAdd(&out[d * HIDDEN + lane], v);
    }
}

// ---------------- layer 2 GEMM: h2 = relu(out1 + b1) @ W2 ; out2 = h2 * dis^2
// NOTE: `in` may alias `out2` — each row is staged to LDS by its own block
// (pre-barrier) and written only by that same block (post-barrier).
__global__ __launch_bounds__(256) void gemm2_kernel(
        const float* __restrict__ in, const float* __restrict__ W2,
        const float* __restrict__ b1, const float* __restrict__ dis,
        float* __restrict__ h2, float* __restrict__ out2) {
    __shared__ float Wl[HIDDEN * HIDDEN];   // 16 KB
    __shared__ float hl[4][HIDDEN];
    int tid = threadIdx.x;
    for (int i = tid; i < HIDDEN * HIDDEN; i += 256) Wl[i] = W2[i];
    int w = tid >> 6, lane = tid & 63;
    int node = blockIdx.x * 4 + w;
    if (node < N_NODES) {
        float v = in[node * HIDDEN + lane] + b1[lane];
        hl[w][lane] = v > 0.f ? v : 0.f;
    }
    __syncthreads();
    if (node < N_NODES) {
        float acc = 0.f;
        #pragma unroll
        for (int k = 0; k < HIDDEN; ++k)
            acc = fmaf(hl[w][k], Wl[k * HIDDEN + lane], acc);
        h2[node * HIDDEN + lane] = acc;
        float d = dis[node];
        out2[node * HIDDEN + lane] = acc * d * d;
    }
}

// ---------------- pooling: pool[batch[i]] += relu(out2[i] + b2); cnt[batch[i]] += 1
__global__ __launch_bounds__(256) void pool_kernel(
        const float* __restrict__ out2, const float* __restrict__ b2,
        const int* __restrict__ batch,
        float* __restrict__ pool, float* __restrict__ cnt) {
    int w = threadIdx.x >> 6, lane = threadIdx.x & 63;
    int node = blockIdx.x * 4 + w;
    if (node < N_NODES) {
        float v = out2[node * HIDDEN + lane] + b2[lane];
        v = v > 0.f ? v : 0.f;
        int g = batch[node];
        atomicAdd(&pool[g * HIDDEN + lane], v);
        if (lane == 0) atomicAdd(&cnt[g], 1.0f);
    }
}

__global__ void final_kernel(const float* __restrict__ pool,
                             const float* __restrict__ cnt,
                             float* __restrict__ out) {
    int i = blockIdx.x * blockDim.x + threadIdx.x;
    if (i < N_GRAPHS * HIDDEN) {
        float c = cnt[i >> 6];
        c = c > 1.0f ? c : 1.0f;
        out[i] = pool[i] / c;
    }
}

extern "C" void kernel_launch(void* const* d_in, const int* in_sizes, int n_in,
                              void* d_out, int out_size, void* d_ws, size_t ws_size,
                              hipStream_t stream) {
    const float* x  = (const float*)d_in[0];
    const float* W1 = (const float*)d_in[1];
    const float* b1 = (const float*)d_in[2];
    const float* W2 = (const float*)d_in[3];
    const float* b2 = (const float*)d_in[4];
    const int* edge_index = (const int*)d_in[5];
    const int* batch      = (const int*)d_in[6];
    float* out = (float*)d_out;

    char* ws = (char*)d_ws;
    size_t off = 0;
    float* dis  = (float*)(ws + off); off += 512 * 1024;                    // deg -> dis
    float* bufA = (float*)(ws + off); off += (size_t)N_NODES * HIDDEN * 4;  // h1, then h2
    float* bufB = (float*)(ws + off); off += (size_t)N_NODES * HIDDEN * 4;  // out1, then out2
    float* pool = (float*)(ws + off); off += (size_t)N_GRAPHS * HIDDEN * 4;
    float* cnt  = (float*)(ws + off); off += (size_t)N_GRAPHS * 4;
    (void)ws_size; (void)in_sizes; (void)n_in; (void)out_size;

    const int* srcv = edge_index;            // edge_index[0]
    const int* dstv = edge_index + N_EDGES;  // edge_index[1]

    // normalization coefficients
    deg_init_kernel<<<(N_NODES + 255) / 256, 256, 0, stream>>>(dis);
    deg_count_kernel<<<(N_EDGES + 255) / 256, 256, 0, stream>>>(dstv, dis);
    dis_kernel<<<(N_NODES + 255) / 256, 256, 0, stream>>>(dis);

    // layer 1
    gemm1_kernel<<<(N_NODES + 3) / 4, 256, 0, stream>>>(x, W1, dis, bufA, bufB);
    scatter_kernel<<<(N_EDGES + 3) / 4, 256, 0, stream>>>(srcv, dstv, dis, bufA, bufB);

    // layer 2 (h2 -> bufA; self-loop init of out2 aliased onto bufB is safe per-row)
    gemm2_kernel<<<(N_NODES + 3) / 4, 256, 0, stream>>>(bufB, W2, b1, dis, bufA, bufB);
    scatter_kernel<<<(N_EDGES + 3) / 4, 256, 0, stream>>>(srcv, dstv, dis, bufA, bufB);

    // pooling
    hipMemsetAsync(pool, 0, (size_t)(N_GRAPHS * HIDDEN + N_GRAPHS) * 4, stream);
    pool_kernel<<<(N_NODES + 3) / 4, 256, 0, stream>>>(bufB, b2, batch, pool, cnt);
    final_kernel<<<(N_GRAPHS * HIDDEN + 255) / 256, 256, 0, stream>>>(pool, cnt, out);
}

// Round 3
// 1173.193 us; speedup vs baseline: 1.6872x; 1.6872x over previous
//
#include <hip/hip_runtime.h>
#include <hip/hip_bf16.h>

#define N_NODES 100000
#define N_EDGES 3200000
#define IN_DIM 128
#define HIDDEN 64
#define N_GRAPHS 512
#define SCAN_BLOCKS 391   // ceil(N_NODES/256)

// ws layout (bytes):
//  [0)        deg_cnt   int[N_NODES]      400000   } zeroed by one memset
//  [400000)   fcnt      int[N_NODES]      400000   }
//  [800000)   pool      float[512*64]     131072   }
//  [931072)   cnt       float[512]          2048   }  total zero region 933120
//  [933120)   partials  int[512]            2048
//  [935168)   dis       float[N_NODES]    400000
//  [1335168)  base      int[N_NODES+1]    400016 (padded)
//  [1735184 -> pad to 1735200) csr        int[N_EDGES] 12800000
//  [14535200) hd        float[N*64]       25600000
//  [40135200) act       float[N*64]       25600000
//  total ~65.7 MB

// ---------------- CSR build ----------------
__global__ void deg_count_kernel(const int* __restrict__ dst, int* __restrict__ deg) {
    int e = blockIdx.x * blockDim.x + threadIdx.x;
    if (e < N_EDGES) atomicAdd(&deg[dst[e]], 1);
}

__global__ __launch_bounds__(256) void scan1_kernel(const int* __restrict__ cnt,
                                                    int* __restrict__ partials) {
    __shared__ int sd[256];
    int t = threadIdx.x;
    int i = blockIdx.x * 256 + t;
    sd[t] = (i < N_NODES) ? cnt[i] : 0;
    __syncthreads();
    for (int s = 128; s > 0; s >>= 1) {
        if (t < s) sd[t] += sd[t + s];
        __syncthreads();
    }
    if (t == 0) partials[blockIdx.x] = sd[0];
}

__global__ __launch_bounds__(512) void scan2_kernel(int* __restrict__ partials) {
    __shared__ int sd[512];
    int t = threadIdx.x;
    int v = (t < SCAN_BLOCKS) ? partials[t] : 0;
    sd[t] = v;
    __syncthreads();
    for (int off = 1; off < 512; off <<= 1) {
        int u = (t >= off) ? sd[t - off] : 0;
        __syncthreads();
        sd[t] += u;
        __syncthreads();
    }
    partials[t] = sd[t] - v;   // exclusive prefix
}

__global__ __launch_bounds__(256) void scan3_kernel(const int* __restrict__ cnt,
                                                    const int* __restrict__ partials,
                                                    int* __restrict__ base,
                                                    float* __restrict__ dis) {
    __shared__ int sd[256];
    int t = threadIdx.x;
    int i = blockIdx.x * 256 + t;
    int v = (i < N_NODES) ? cnt[i] : 0;
    sd[t] = v;
    __syncthreads();
    for (int off = 1; off < 256; off <<= 1) {
        int u = (t >= off) ? sd[t - off] : 0;
        __syncthreads();
        sd[t] += u;
        __syncthreads();
    }
    if (i < N_NODES) {
        base[i] = partials[blockIdx.x] + sd[t] - v;     // exclusive
        dis[i] = rsqrtf((float)(v + 1));                // +1 self-loop
    }
    if (blockIdx.x == 0 && t == 0) base[N_NODES] = N_EDGES;
}

__global__ void fill_kernel(const int* __restrict__ src, const int* __restrict__ dst,
                            const int* __restrict__ base, int* __restrict__ fcnt,
                            int* __restrict__ csr) {
    int e = blockIdx.x * blockDim.x + threadIdx.x;
    if (e < N_EDGES) {
        int d = dst[e];
        int pos = base[d] + atomicAdd(&fcnt[d], 1);
        csr[pos] = src[e];
    }
}

// ---------------- GEMM: hd[node] = (in[node] @ W) * dis[node] ----------------
// wave-per-node, grid-stride; W staged to LDS once per block.
template <int K>
__global__ __launch_bounds__(256) void gemm_kernel(
        const float* __restrict__ in, const float* __restrict__ W,
        const float* __restrict__ dis, float* __restrict__ hd) {
    __shared__ float Wl[K * HIDDEN];
    int tid = threadIdx.x;
    for (int i = tid; i < K * HIDDEN; i += 256) Wl[i] = W[i];
    __syncthreads();
    int w = tid >> 6, lane = tid & 63;
    int stride = gridDim.x * 4;
    for (int node = blockIdx.x * 4 + w; node < N_NODES; node += stride) {
        float acc = 0.f;
        #pragma unroll
        for (int k = 0; k < K; ++k)
            acc = fmaf(in[(size_t)node * K + k], Wl[k * HIDDEN + lane], acc);
        hd[(size_t)node * HIDDEN + lane] = acc * dis[node];
    }
}

// ---------------- pull: row = dis[d]*(sum_src hd[src] + hd[d]) + bias --------
// POOL=0: act[d] = relu(row).  POOL=1: atomic mean-pool accumulation of relu(row).
template <int POOL>
__global__ __launch_bounds__(256) void pull_kernel(
        const float* __restrict__ hd, const float* __restrict__ dis,
        const int* __restrict__ base, const int* __restrict__ csr,
        const float* __restrict__ bias,
        float* __restrict__ act,
        const int* __restrict__ batch, float* __restrict__ pool,
        float* __restrict__ cnt) {
    int w = threadIdx.x >> 6, lane = threadIdx.x & 63;
    int node = blockIdx.x * 4 + w;
    if (node >= N_NODES) return;   // whole-wave uniform exit
    int beg = base[node], end = base[node + 1];
    float a0 = 0.f, a1 = 0.f, a2 = 0.f, a3 = 0.f;
    for (int j = beg; j < end; j += 64) {
        int rem = end - j;
        int m = rem < 64 ? rem : 64;
        int idx = (lane < m) ? csr[j + lane] : 0;
        int t = 0;
        for (; t + 4 <= m; t += 4) {
            int s0 = __shfl(idx, t);
            int s1 = __shfl(idx, t + 1);
            int s2 = __shfl(idx, t + 2);
            int s3 = __shfl(idx, t + 3);
            a0 += hd[(size_t)s0 * HIDDEN + lane];
            a1 += hd[(size_t)s1 * HIDDEN + lane];
            a2 += hd[(size_t)s2 * HIDDEN + lane];
            a3 += hd[(size_t)s3 * HIDDEN + lane];
        }
        for (; t < m; ++t) {
            int s = __shfl(idx, t);
            a0 += hd[(size_t)s * HIDDEN + lane];
        }
    }
    float acc = (a0 + a1) + (a2 + a3);
    float row = dis[node] * (acc + hd[(size_t)node * HIDDEN + lane]) + bias[lane];
    float v = row > 0.f ? row : 0.f;
    if (POOL == 0) {
        act[(size_t)node * HIDDEN + lane] = v;
    } else {
        int g = batch[node];
        atomicAdd(&pool[g * HIDDEN + lane], v);
        if (lane == 0) atomicAdd(&cnt[g], 1.0f);
    }
}

__global__ void final_kernel(const float* __restrict__ pool,
                             const float* __restrict__ cnt,
                             float* __restrict__ out) {
    int i = blockIdx.x * blockDim.x + threadIdx.x;
    if (i < N_GRAPHS * HIDDEN) {
        float c = cnt[i >> 6];
        c = c > 1.0f ? c : 1.0f;
        out[i] = pool[i] / c;
    }
}

extern "C" void kernel_launch(void* const* d_in, const int* in_sizes, int n_in,
                              void* d_out, int out_size, void* d_ws, size_t ws_size,
                              hipStream_t stream) {
    const float* x  = (const float*)d_in[0];
    const float* W1 = (const float*)d_in[1];
    const float* b1 = (const float*)d_in[2];
    const float* W2 = (const float*)d_in[3];
    const float* b2 = (const float*)d_in[4];
    const int* edge_index = (const int*)d_in[5];
    const int* batch      = (const int*)d_in[6];
    float* out = (float*)d_out;
    (void)in_sizes; (void)n_in; (void)out_size; (void)ws_size;

    char* ws = (char*)d_ws;
    int*   deg_cnt  = (int*)  (ws + 0);
    int*   fcnt     = (int*)  (ws + 400000);
    float* pool     = (float*)(ws + 800000);
    float* cnt      = (float*)(ws + 931072);
    int*   partials = (int*)  (ws + 933120);
    float* dis      = (float*)(ws + 935168);
    int*   base     = (int*)  (ws + 1335168);
    int*   csr      = (int*)  (ws + 1735200);
    float* hd       = (float*)(ws + 14535200);
    float* act      = (float*)(ws + 40135200);

    const int* srcv = edge_index;            // edge_index[0]
    const int* dstv = edge_index + N_EDGES;  // edge_index[1]

    // zero: deg_cnt, fcnt, pool, cnt (contiguous region)
    hipMemsetAsync(ws, 0, 933120, stream);

    // CSR build (reused by both layers)
    deg_count_kernel<<<(N_EDGES + 255) / 256, 256, 0, stream>>>(dstv, deg_cnt);
    scan1_kernel<<<SCAN_BLOCKS, 256, 0, stream>>>(deg_cnt, partials);
    scan2_kernel<<<1, 512, 0, stream>>>(partials);
    scan3_kernel<<<SCAN_BLOCKS, 256, 0, stream>>>(deg_cnt, partials, base, dis);
    fill_kernel<<<(N_EDGES + 255) / 256, 256, 0, stream>>>(srcv, dstv, base, fcnt, csr);

    // layer 1: hd = (x@W1)*dis ; act = relu(dis*(gather+self) + b1)
    gemm_kernel<IN_DIM><<<1024, 256, 0, stream>>>(x, W1, dis, hd);
    pull_kernel<0><<<(N_NODES + 3) / 4, 256, 0, stream>>>(hd, dis, base, csr, b1,
                                                          act, nullptr, nullptr, nullptr);

    // layer 2: hd = (act@W2)*dis ; fused relu+b2+mean-pool atomics
    gemm_kernel<HIDDEN><<<1024, 256, 0, stream>>>(act, W2, dis, hd);
    pull_kernel<1><<<(N_NODES + 3) / 4, 256, 0, stream>>>(hd, dis, base, csr, b2,
                                                          nullptr, batch, pool, cnt);

    final_kernel<<<(N_GRAPHS * HIDDEN + 255) / 256, 256, 0, stream>>>(pool, cnt, out);
}

// Round 4
// 957.162 us; speedup vs baseline: 2.0680x; 1.2257x over previous
//
#include <hip/hip_runtime.h>
#include <hip/hip_bf16.h>

#define N_NODES 100000
#define N_EDGES 3200000
#define IN_DIM 128
#define HIDDEN 64
#define N_GRAPHS 512
#define SCAN_BLOCKS 391   // ceil(N_NODES/256)

// ---------------- CSR build ----------------
__global__ void deg_count_kernel(const int* __restrict__ dst, int* __restrict__ deg) {
    int e = blockIdx.x * blockDim.x + threadIdx.x;
    if (e < N_EDGES) atomicAdd(&deg[dst[e]], 1);
}

__global__ __launch_bounds__(256) void scan1_kernel(const int* __restrict__ cnt,
                                                    int* __restrict__ partials) {
    __shared__ int sd[256];
    int t = threadIdx.x;
    int i = blockIdx.x * 256 + t;
    sd[t] = (i < N_NODES) ? cnt[i] : 0;
    __syncthreads();
    for (int s = 128; s > 0; s >>= 1) {
        if (t < s) sd[t] += sd[t + s];
        __syncthreads();
    }
    if (t == 0) partials[blockIdx.x] = sd[0];
}

__global__ __launch_bounds__(512) void scan2_kernel(int* __restrict__ partials) {
    __shared__ int sd[512];
    int t = threadIdx.x;
    int v = (t < SCAN_BLOCKS) ? partials[t] : 0;
    sd[t] = v;
    __syncthreads();
    for (int off = 1; off < 512; off <<= 1) {
        int u = (t >= off) ? sd[t - off] : 0;
        __syncthreads();
        sd[t] += u;
        __syncthreads();
    }
    partials[t] = sd[t] - v;   // exclusive prefix
}

__global__ __launch_bounds__(256) void scan3_kernel(const int* __restrict__ cnt,
                                                    const int* __restrict__ partials,
                                                    int* __restrict__ base,
                                                    float* __restrict__ dis) {
    __shared__ int sd[256];
    int t = threadIdx.x;
    int i = blockIdx.x * 256 + t;
    int v = (i < N_NODES) ? cnt[i] : 0;
    sd[t] = v;
    __syncthreads();
    for (int off = 1; off < 256; off <<= 1) {
        int u = (t >= off) ? sd[t - off] : 0;
        __syncthreads();
        sd[t] += u;
        __syncthreads();
    }
    if (i < N_NODES) {
        base[i] = partials[blockIdx.x] + sd[t] - v;     // exclusive
        dis[i] = rsqrtf((float)(v + 1));                // +1 self-loop
    }
    if (blockIdx.x == 0 && t == 0) base[N_NODES] = N_EDGES;
}

__global__ void fill_kernel(const int* __restrict__ src, const int* __restrict__ dst,
                            const int* __restrict__ base, int* __restrict__ fcnt,
                            int* __restrict__ csr) {
    int e = blockIdx.x * blockDim.x + threadIdx.x;
    if (e < N_EDGES) {
        int d = dst[e];
        int pos = base[d] + atomicAdd(&fcnt[d], 1);
        csr[pos] = src[e];
    }
}

// ---------------- GEMM: hd[node] = (in[node] @ W) * dis[node] ----------------
// Each lane holds its W column in VGPRs; node index forced wave-uniform so the
// x-row loads compile to s_load through the scalar cache. Inner loop = pure
// v_fmac_f32(v, s, v). 4 nodes/iter for scalar-load ILP. No LDS.
template <int K>
__global__ __launch_bounds__(256) void gemm_kernel(
        const float* __restrict__ in, const float* __restrict__ W,
        const float* __restrict__ dis, float* __restrict__ hd) {
    int tid = threadIdx.x;
    int lane = tid & 63;
    float Wr[K];
    #pragma unroll
    for (int k = 0; k < K; ++k) Wr[k] = W[k * HIDDEN + lane];   // coalesced
    int w = __builtin_amdgcn_readfirstlane(tid >> 6);           // provably uniform
    int wave = blockIdx.x * 4 + w;
    int nw = gridDim.x * 4;
    // N_NODES % 4 == 0 and n0 is a multiple of 4 -> always 4 full rows.
    for (int n0 = wave * 4; n0 < N_NODES; n0 += nw * 4) {
        const float* xr = in + (size_t)n0 * K;
        float a0 = 0.f, a1 = 0.f, a2 = 0.f, a3 = 0.f;
        #pragma unroll
        for (int k = 0; k < K; ++k) {
            float wv = Wr[k];
            a0 = fmaf(xr[k],         wv, a0);
            a1 = fmaf(xr[K + k],     wv, a1);
            a2 = fmaf(xr[2 * K + k], wv, a2);
            a3 = fmaf(xr[3 * K + k], wv, a3);
        }
        float* o = hd + (size_t)n0 * HIDDEN + lane;
        o[0]          = a0 * dis[n0];
        o[HIDDEN]     = a1 * dis[n0 + 1];
        o[2 * HIDDEN] = a2 * dis[n0 + 2];
        o[3 * HIDDEN] = a3 * dis[n0 + 3];
    }
}

// ---------------- pull: row = dis[d]*(sum_src hd[src] + hd[d]) + bias --------
// POOL=0: act[d] = relu(row).  POOL=1: atomic mean-pool accumulation of relu(row).
template <int POOL>
__global__ __launch_bounds__(256) void pull_kernel(
        const float* __restrict__ hd, const float* __restrict__ dis,
        const int* __restrict__ base, const int* __restrict__ csr,
        const float* __restrict__ bias,
        float* __restrict__ act,
        const int* __restrict__ batch, float* __restrict__ pool,
        float* __restrict__ cnt) {
    int w = threadIdx.x >> 6, lane = threadIdx.x & 63;
    int node = blockIdx.x * 4 + w;
    if (node >= N_NODES) return;   // whole-wave uniform exit
    int beg = base[node], end = base[node + 1];
    float a0 = 0.f, a1 = 0.f, a2 = 0.f, a3 = 0.f;
    for (int j = beg; j < end; j += 64) {
        int rem = end - j;
        int m = rem < 64 ? rem : 64;
        int idx = (lane < m) ? csr[j + lane] : 0;
        int t = 0;
        for (; t + 4 <= m; t += 4) {
            int s0 = __shfl(idx, t);
            int s1 = __shfl(idx, t + 1);
            int s2 = __shfl(idx, t + 2);
            int s3 = __shfl(idx, t + 3);
            a0 += hd[(size_t)s0 * HIDDEN + lane];
            a1 += hd[(size_t)s1 * HIDDEN + lane];
            a2 += hd[(size_t)s2 * HIDDEN + lane];
            a3 += hd[(size_t)s3 * HIDDEN + lane];
        }
        for (; t < m; ++t) {
            int s = __shfl(idx, t);
            a0 += hd[(size_t)s * HIDDEN + lane];
        }
    }
    float acc = (a0 + a1) + (a2 + a3);
    float row = dis[node] * (acc + hd[(size_t)node * HIDDEN + lane]) + bias[lane];
    float v = row > 0.f ? row : 0.f;
    if (POOL == 0) {
        act[(size_t)node * HIDDEN + lane] = v;
    } else {
        int g = batch[node];
        atomicAdd(&pool[g * HIDDEN + lane], v);
        if (lane == 0) atomicAdd(&cnt[g], 1.0f);
    }
}

__global__ void final_kernel(const float* __restrict__ pool,
                             const float* __restrict__ cnt,
                             float* __restrict__ out) {
    int i = blockIdx.x * blockDim.x + threadIdx.x;
    if (i < N_GRAPHS * HIDDEN) {
        float c = cnt[i >> 6];
        c = c > 1.0f ? c : 1.0f;
        out[i] = pool[i] / c;
    }
}

extern "C" void kernel_launch(void* const* d_in, const int* in_sizes, int n_in,
                              void* d_out, int out_size, void* d_ws, size_t ws_size,
                              hipStream_t stream) {
    const float* x  = (const float*)d_in[0];
    const float* W1 = (const float*)d_in[1];
    const float* b1 = (const float*)d_in[2];
    const float* W2 = (const float*)d_in[3];
    const float* b2 = (const float*)d_in[4];
    const int* edge_index = (const int*)d_in[5];
    const int* batch      = (const int*)d_in[6];
    float* out = (float*)d_out;
    (void)in_sizes; (void)n_in; (void)out_size; (void)ws_size;

    char* ws = (char*)d_ws;
    int*   deg_cnt  = (int*)  (ws + 0);
    int*   fcnt     = (int*)  (ws + 400000);
    float* pool     = (float*)(ws + 800000);
    float* cnt      = (float*)(ws + 931072);
    int*   partials = (int*)  (ws + 933120);
    float* dis      = (float*)(ws + 935168);
    int*   base     = (int*)  (ws + 1335168);
    int*   csr      = (int*)  (ws + 1735200);
    float* hd       = (float*)(ws + 14535200);
    float* act      = (float*)(ws + 40135200);

    const int* srcv = edge_index;            // edge_index[0]
    const int* dstv = edge_index + N_EDGES;  // edge_index[1]

    // zero: deg_cnt, fcnt, pool, cnt (contiguous region)
    hipMemsetAsync(ws, 0, 933120, stream);

    // CSR build (reused by both layers)
    deg_count_kernel<<<(N_EDGES + 255) / 256, 256, 0, stream>>>(dstv, deg_cnt);
    scan1_kernel<<<SCAN_BLOCKS, 256, 0, stream>>>(deg_cnt, partials);
    scan2_kernel<<<1, 512, 0, stream>>>(partials);
    scan3_kernel<<<SCAN_BLOCKS, 256, 0, stream>>>(deg_cnt, partials, base, dis);
    fill_kernel<<<(N_EDGES + 255) / 256, 256, 0, stream>>>(srcv, dstv, base, fcnt, csr);

    // layer 1: hd = (x@W1)*dis ; act = relu(dis*(gather+self) + b1)
    gemm_kernel<IN_DIM><<<1024, 256, 0, stream>>>(x, W1, dis, hd);
    pull_kernel<0><<<(N_NODES + 3) / 4, 256, 0, stream>>>(hd, dis, base, csr, b1,
                                                          act, nullptr, nullptr, nullptr);

    // layer 2: hd = (act@W2)*dis ; fused relu+b2+mean-pool atomics
    gemm_kernel<HIDDEN><<<1024, 256, 0, stream>>>(act, W2, dis, hd);
    pull_kernel<1><<<(N_NODES + 3) / 4, 256, 0, stream>>>(hd, dis, base, csr, b2,
                                                          nullptr, batch, pool, cnt);

    final_kernel<<<(N_GRAPHS * HIDDEN + 255) / 256, 256, 0, stream>>>(pool, cnt, out);
}

// Round 5
// 877.776 us; speedup vs baseline: 2.2550x; 1.0904x over previous
//
#include <hip/hip_runtime.h>
#include <hip/hip_bf16.h>

#define N_NODES 100000
#define N_EDGES 3200000
#define IN_DIM 128
#define HIDDEN 64
#define N_GRAPHS 512
#define SCAN_BLOCKS 391   // ceil(N_NODES/256)

typedef __hip_bfloat16 bf16;
__device__ __forceinline__ float b2f(bf16 v) { return __bfloat162float(v); }

// ---------------- CSR build ----------------
__global__ void deg_count_kernel(const int* __restrict__ dst, int* __restrict__ deg) {
    int e = blockIdx.x * blockDim.x + threadIdx.x;
    if (e < N_EDGES) atomicAdd(&deg[dst[e]], 1);
}

__global__ __launch_bounds__(256) void scan1_kernel(const int* __restrict__ cnt,
                                                    int* __restrict__ partials) {
    __shared__ int sd[256];
    int t = threadIdx.x;
    int i = blockIdx.x * 256 + t;
    sd[t] = (i < N_NODES) ? cnt[i] : 0;
    __syncthreads();
    for (int s = 128; s > 0; s >>= 1) {
        if (t < s) sd[t] += sd[t + s];
        __syncthreads();
    }
    if (t == 0) partials[blockIdx.x] = sd[0];
}

__global__ __launch_bounds__(512) void scan2_kernel(int* __restrict__ partials) {
    __shared__ int sd[512];
    int t = threadIdx.x;
    int v = (t < SCAN_BLOCKS) ? partials[t] : 0;
    sd[t] = v;
    __syncthreads();
    for (int off = 1; off < 512; off <<= 1) {
        int u = (t >= off) ? sd[t - off] : 0;
        __syncthreads();
        sd[t] += u;
        __syncthreads();
    }
    partials[t] = sd[t] - v;   // exclusive prefix
}

__global__ __launch_bounds__(256) void scan3_kernel(const int* __restrict__ cnt,
                                                    const int* __restrict__ partials,
                                                    int* __restrict__ base,
                                                    float* __restrict__ dis) {
    __shared__ int sd[256];
    int t = threadIdx.x;
    int i = blockIdx.x * 256 + t;
    int v = (i < N_NODES) ? cnt[i] : 0;
    sd[t] = v;
    __syncthreads();
    for (int off = 1; off < 256; off <<= 1) {
        int u = (t >= off) ? sd[t - off] : 0;
        __syncthreads();
        sd[t] += u;
        __syncthreads();
    }
    if (i < N_NODES) {
        base[i] = partials[blockIdx.x] + sd[t] - v;     // exclusive
        dis[i] = rsqrtf((float)(v + 1));                // +1 self-loop
    }
    if (blockIdx.x == 0 && t == 0) base[N_NODES] = N_EDGES;
}

__global__ void fill_kernel(const int* __restrict__ src, const int* __restrict__ dst,
                            const int* __restrict__ base, int* __restrict__ fcnt,
                            int* __restrict__ csr) {
    int e = blockIdx.x * blockDim.x + threadIdx.x;
    if (e < N_EDGES) {
        int d = dst[e];
        int pos = base[d] + atomicAdd(&fcnt[d], 1);
        csr[pos] = src[e];
    }
}

// ---------------- GEMM: hd[node] = bf16((in[node] @ W) * dis[node]) ----------
// Lane-resident W column + wave-uniform x-row via scalar cache; pure v_fmac.
template <int K>
__global__ __launch_bounds__(256) void gemm_kernel(
        const float* __restrict__ in, const float* __restrict__ W,
        const float* __restrict__ dis, bf16* __restrict__ hd) {
    int tid = threadIdx.x;
    int lane = tid & 63;
    float Wr[K];
    #pragma unroll
    for (int k = 0; k < K; ++k) Wr[k] = W[k * HIDDEN + lane];   // coalesced
    int w = __builtin_amdgcn_readfirstlane(tid >> 6);           // provably uniform
    int wave = blockIdx.x * 4 + w;
    int nw = gridDim.x * 4;
    for (int n0 = wave * 4; n0 < N_NODES; n0 += nw * 4) {
        const float* xr = in + (size_t)n0 * K;
        float a0 = 0.f, a1 = 0.f, a2 = 0.f, a3 = 0.f;
        #pragma unroll
        for (int k = 0; k < K; ++k) {
            float wv = Wr[k];
            a0 = fmaf(xr[k],         wv, a0);
            a1 = fmaf(xr[K + k],     wv, a1);
            a2 = fmaf(xr[2 * K + k], wv, a2);
            a3 = fmaf(xr[3 * K + k], wv, a3);
        }
        bf16* o = hd + (size_t)n0 * HIDDEN + lane;
        o[0]          = __float2bfloat16(a0 * dis[n0]);
        o[HIDDEN]     = __float2bfloat16(a1 * dis[n0 + 1]);
        o[2 * HIDDEN] = __float2bfloat16(a2 * dis[n0 + 2]);
        o[3 * HIDDEN] = __float2bfloat16(a3 * dis[n0 + 3]);
    }
}

// ---------------- pull: row = dis[d]*(sum_src hd[src] + hd[d]) + bias --------
// bf16 hd rows: one 128 B L2 line per gather. 8 independent loads in flight.
// POOL=0: act[d] = relu(row) (f32). POOL=1: atomic mean-pool of relu(row).
template <int POOL>
__global__ __launch_bounds__(256) void pull_kernel(
        const bf16* __restrict__ hd, const float* __restrict__ dis,
        const int* __restrict__ base, const int* __restrict__ csr,
        const float* __restrict__ bias,
        float* __restrict__ act,
        const int* __restrict__ batch, float* __restrict__ pool,
        float* __restrict__ cnt) {
    int w = threadIdx.x >> 6, lane = threadIdx.x & 63;
    int node = blockIdx.x * 4 + w;
    if (node >= N_NODES) return;   // whole-wave uniform exit
    int beg = base[node], end = base[node + 1];
    float a0 = 0.f, a1 = 0.f, a2 = 0.f, a3 = 0.f;
    for (int j = beg; j < end; j += 64) {
        int rem = end - j;
        int m = rem < 64 ? rem : 64;
        int idx = (lane < m) ? csr[j + lane] : 0;
        int t = 0;
        for (; t + 8 <= m; t += 8) {
            int s0 = __shfl(idx, t);
            int s1 = __shfl(idx, t + 1);
            int s2 = __shfl(idx, t + 2);
            int s3 = __shfl(idx, t + 3);
            int s4 = __shfl(idx, t + 4);
            int s5 = __shfl(idx, t + 5);
            int s6 = __shfl(idx, t + 6);
            int s7 = __shfl(idx, t + 7);
            float v0 = b2f(hd[(size_t)s0 * HIDDEN + lane]);
            float v1 = b2f(hd[(size_t)s1 * HIDDEN + lane]);
            float v2 = b2f(hd[(size_t)s2 * HIDDEN + lane]);
            float v3 = b2f(hd[(size_t)s3 * HIDDEN + lane]);
            float v4 = b2f(hd[(size_t)s4 * HIDDEN + lane]);
            float v5 = b2f(hd[(size_t)s5 * HIDDEN + lane]);
            float v6 = b2f(hd[(size_t)s6 * HIDDEN + lane]);
            float v7 = b2f(hd[(size_t)s7 * HIDDEN + lane]);
            a0 += v0 + v4;
            a1 += v1 + v5;
            a2 += v2 + v6;
            a3 += v3 + v7;
        }
        for (; t < m; ++t) {
            int s = __shfl(idx, t);
            a0 += b2f(hd[(size_t)s * HIDDEN + lane]);
        }
    }
    float acc = (a0 + a1) + (a2 + a3);
    float self = b2f(hd[(size_t)node * HIDDEN + lane]);
    float row = dis[node] * (acc + self) + bias[lane];
    float v = row > 0.f ? row : 0.f;
    if (POOL == 0) {
        act[(size_t)node * HIDDEN + lane] = v;
    } else {
        int g = batch[node];
        atomicAdd(&pool[g * HIDDEN + lane], v);
        if (lane == 0) atomicAdd(&cnt[g], 1.0f);
    }
}

__global__ void final_kernel(const float* __restrict__ pool,
                             const float* __restrict__ cnt,
                             float* __restrict__ out) {
    int i = blockIdx.x * blockDim.x + threadIdx.x;
    if (i < N_GRAPHS * HIDDEN) {
        float c = cnt[i >> 6];
        c = c > 1.0f ? c : 1.0f;
        out[i] = pool[i] / c;
    }
}

extern "C" void kernel_launch(void* const* d_in, const int* in_sizes, int n_in,
                              void* d_out, int out_size, void* d_ws, size_t ws_size,
                              hipStream_t stream) {
    const float* x  = (const float*)d_in[0];
    const float* W1 = (const float*)d_in[1];
    const float* b1 = (const float*)d_in[2];
    const float* W2 = (const float*)d_in[3];
    const float* b2 = (const float*)d_in[4];
    const int* edge_index = (const int*)d_in[5];
    const int* batch      = (const int*)d_in[6];
    float* out = (float*)d_out;
    (void)in_sizes; (void)n_in; (void)out_size; (void)ws_size;

    char* ws = (char*)d_ws;
    int*   deg_cnt  = (int*)  (ws + 0);         // 400000
    int*   fcnt     = (int*)  (ws + 400000);    // 400000
    float* pool     = (float*)(ws + 800000);    // 131072
    float* cnt      = (float*)(ws + 931072);    // 2048
    int*   partials = (int*)  (ws + 933120);    // 2048
    float* dis      = (float*)(ws + 935168);    // 400000
    int*   base     = (int*)  (ws + 1335168);   // 400032 (padded)
    int*   csr      = (int*)  (ws + 1735200);   // 12800000
    bf16*  hd       = (bf16*) (ws + 14535200);  // 12800000
    float* act      = (float*)(ws + 27335200);  // 25600000 -> ends 52935200

    const int* srcv = edge_index;            // edge_index[0]
    const int* dstv = edge_index + N_EDGES;  // edge_index[1]

    // zero: deg_cnt, fcnt, pool, cnt (contiguous region)
    hipMemsetAsync(ws, 0, 933120, stream);

    // CSR build (reused by both layers)
    deg_count_kernel<<<(N_EDGES + 255) / 256, 256, 0, stream>>>(dstv, deg_cnt);
    scan1_kernel<<<SCAN_BLOCKS, 256, 0, stream>>>(deg_cnt, partials);
    scan2_kernel<<<1, 512, 0, stream>>>(partials);
    scan3_kernel<<<SCAN_BLOCKS, 256, 0, stream>>>(deg_cnt, partials, base, dis);
    fill_kernel<<<(N_EDGES + 255) / 256, 256, 0, stream>>>(srcv, dstv, base, fcnt, csr);

    // layer 1: hd = bf16((x@W1)*dis) ; act = relu(dis*(gather+self) + b1)
    gemm_kernel<IN_DIM><<<1024, 256, 0, stream>>>(x, W1, dis, hd);
    pull_kernel<0><<<(N_NODES + 3) / 4, 256, 0, stream>>>(hd, dis, base, csr, b1,
                                                          act, nullptr, nullptr, nullptr);

    // layer 2: hd = bf16((act@W2)*dis) ; fused relu+b2+mean-pool atomics
    gemm_kernel<HIDDEN><<<1024, 256, 0, stream>>>(act, W2, dis, hd);
    pull_kernel<1><<<(N_NODES + 3) / 4, 256, 0, stream>>>(hd, dis, base, csr, b2,
                                                          nullptr, batch, pool, cnt);

    final_kernel<<<(N_GRAPHS * HIDDEN + 255) / 256, 256, 0, stream>>>(pool, cnt, out);
}